// Round 1
// baseline (1521.315 us; speedup 1.0000x reference)
//
#include <hip/hip_runtime.h>
#include <math.h>

#define N_NODES  100000
#define N_EDGES  3200000
#define N_GRAPHS 512
#define DCH      24
#define NLAYERS  4

// ---------------- linear kernel: q,k,v,skip = h @ W* + b* ----------------
__global__ __launch_bounds__(256) void lin_kernel(
    const float* __restrict__ h,
    const float* __restrict__ Wq, const float* __restrict__ bq,
    const float* __restrict__ Wk, const float* __restrict__ bk,
    const float* __restrict__ Wv, const float* __restrict__ bv,
    const float* __restrict__ Ws, const float* __restrict__ bs,
    float* __restrict__ q, float* __restrict__ k, float* __restrict__ v,
    float* __restrict__ skip)
{
    __shared__ float sW[4 * 576];
    __shared__ float sb[4 * 24];
    for (int i = threadIdx.x; i < 576; i += blockDim.x) {
        sW[0 * 576 + i] = Wq[i];
        sW[1 * 576 + i] = Wk[i];
        sW[2 * 576 + i] = Wv[i];
        sW[3 * 576 + i] = Ws[i];
    }
    if (threadIdx.x < 24) {
        sb[0 * 24 + threadIdx.x] = bq[threadIdx.x];
        sb[1 * 24 + threadIdx.x] = bk[threadIdx.x];
        sb[2 * 24 + threadIdx.x] = bv[threadIdx.x];
        sb[3 * 24 + threadIdx.x] = bs[threadIdx.x];
    }
    __syncthreads();

    int node = blockIdx.x * blockDim.x + threadIdx.x;
    if (node >= N_NODES) return;

    float hx[24];
    const float4* hp = (const float4*)(h + (size_t)node * DCH);
    #pragma unroll
    for (int t = 0; t < 6; t++) {
        float4 f = hp[t];
        hx[4*t] = f.x; hx[4*t+1] = f.y; hx[4*t+2] = f.z; hx[4*t+3] = f.w;
    }

    float* outs[4] = {q, k, v, skip};
    #pragma unroll
    for (int mtx = 0; mtx < 4; mtx++) {
        float o[24];
        #pragma unroll
        for (int c = 0; c < 24; c++) o[c] = sb[mtx * 24 + c];
        #pragma unroll
        for (int ci = 0; ci < 24; ci++) {
            float hv = hx[ci];
            #pragma unroll
            for (int c = 0; c < 24; c++)
                o[c] += hv * sW[mtx * 576 + ci * 24 + c];
        }
        float4* op = (float4*)(outs[mtx] + (size_t)node * DCH);
        #pragma unroll
        for (int t = 0; t < 6; t++) {
            float4 f;
            f.x = o[4*t]; f.y = o[4*t+1]; f.z = o[4*t+2]; f.w = o[4*t+3];
            op[t] = f;
        }
    }
}

// ---------------- CSR build ----------------
__global__ void hist_kernel(const int* __restrict__ dst, int* __restrict__ counts)
{
    int e = blockIdx.x * blockDim.x + threadIdx.x;
    if (e < N_EDGES) atomicAdd(&counts[dst[e]], 1);
}

__global__ __launch_bounds__(1024) void scan1_kernel(
    const int* __restrict__ counts, int* __restrict__ row_start, int* __restrict__ bsums)
{
    __shared__ int sd[1024];
    int gid = blockIdx.x * 1024 + threadIdx.x;
    int vin = (gid < N_NODES) ? counts[gid] : 0;
    sd[threadIdx.x] = vin;
    __syncthreads();
    for (int off = 1; off < 1024; off <<= 1) {
        int t = (threadIdx.x >= off) ? sd[threadIdx.x - off] : 0;
        __syncthreads();
        sd[threadIdx.x] += t;
        __syncthreads();
    }
    int incl = sd[threadIdx.x];
    if (gid < N_NODES) row_start[gid] = incl - vin;  // block-local exclusive
    if (threadIdx.x == 1023) bsums[blockIdx.x] = incl;
}

__global__ __launch_bounds__(128) void scan2_kernel(int* __restrict__ bsums, int nb)
{
    __shared__ int sd[128];
    int v = (threadIdx.x < nb) ? bsums[threadIdx.x] : 0;
    sd[threadIdx.x] = v;
    __syncthreads();
    for (int off = 1; off < 128; off <<= 1) {
        int t = (threadIdx.x >= off) ? sd[threadIdx.x - off] : 0;
        __syncthreads();
        sd[threadIdx.x] += t;
        __syncthreads();
    }
    if (threadIdx.x < nb) bsums[threadIdx.x] = sd[threadIdx.x] - v;  // exclusive
}

__global__ void scan3_kernel(int* __restrict__ row_start, const int* __restrict__ bsums)
{
    int gid = blockIdx.x * blockDim.x + threadIdx.x;
    if (gid < N_NODES) row_start[gid] += bsums[gid >> 10];
}

__global__ void scatter_kernel(
    const int* __restrict__ src, const int* __restrict__ dst,
    const int* __restrict__ row_start, int* __restrict__ cursor,
    int* __restrict__ csr_src)
{
    int e = blockIdx.x * blockDim.x + threadIdx.x;
    if (e < N_EDGES) {
        int d = dst[e];
        int pos = row_start[d] + atomicAdd(&cursor[d], 1);
        csr_src[pos] = src[e];
    }
}

// ---------------- attention: online softmax per dst node ----------------
__global__ __launch_bounds__(256) void attn_kernel(
    const float* __restrict__ q, const float* __restrict__ k, const float* __restrict__ v,
    const float* __restrict__ skip,
    const int* __restrict__ row_start, const int* __restrict__ counts,
    const int* __restrict__ csr_src,
    float* __restrict__ out)
{
    int i = blockIdx.x * blockDim.x + threadIdx.x;
    if (i >= N_NODES) return;

    float qr[24];
    const float4* qp = (const float4*)(q + (size_t)i * DCH);
    #pragma unroll
    for (int t = 0; t < 6; t++) {
        float4 f = qp[t];
        qr[4*t] = f.x; qr[4*t+1] = f.y; qr[4*t+2] = f.z; qr[4*t+3] = f.w;
    }

    float m = -INFINITY, s = 0.f;
    float acc[24];
    #pragma unroll
    for (int c = 0; c < 24; c++) acc[c] = 0.f;

    int beg = row_start[i];
    int cnt = counts[i];
    const float scale = 0.2041241452319315f;  // 1/sqrt(24)

    for (int e = 0; e < cnt; e++) {
        int src = csr_src[beg + e];
        const float4* kp = (const float4*)(k + (size_t)src * DCH);
        float4 kk[6];
        #pragma unroll
        for (int t = 0; t < 6; t++) kk[t] = kp[t];
        float dot = 0.f;
        #pragma unroll
        for (int t = 0; t < 6; t++)
            dot += qr[4*t]*kk[t].x + qr[4*t+1]*kk[t].y + qr[4*t+2]*kk[t].z + qr[4*t+3]*kk[t].w;
        dot *= scale;

        const float4* vp = (const float4*)(v + (size_t)src * DCH);
        float4 vv[6];
        #pragma unroll
        for (int t = 0; t < 6; t++) vv[t] = vp[t];

        if (dot > m) {
            float sc = __expf(m - dot);   // first iter: exp(-inf) = 0
            s = s * sc + 1.f;
            #pragma unroll
            for (int t = 0; t < 6; t++) {
                acc[4*t]   = acc[4*t]   * sc + vv[t].x;
                acc[4*t+1] = acc[4*t+1] * sc + vv[t].y;
                acc[4*t+2] = acc[4*t+2] * sc + vv[t].z;
                acc[4*t+3] = acc[4*t+3] * sc + vv[t].w;
            }
            m = dot;
        } else {
            float w = __expf(dot - m);
            s += w;
            #pragma unroll
            for (int t = 0; t < 6; t++) {
                acc[4*t]   += w * vv[t].x;
                acc[4*t+1] += w * vv[t].y;
                acc[4*t+2] += w * vv[t].z;
                acc[4*t+3] += w * vv[t].w;
            }
        }
    }

    float inv = 1.f / (s + 1e-16f);
    const float4* sp = (const float4*)(skip + (size_t)i * DCH);
    float4* op = (float4*)(out + (size_t)i * DCH);
    #pragma unroll
    for (int t = 0; t < 6; t++) {
        float4 sk = sp[t];
        float4 r;
        r.x = fmaxf(sk.x + acc[4*t]   * inv, 0.f);
        r.y = fmaxf(sk.y + acc[4*t+1] * inv, 0.f);
        r.z = fmaxf(sk.z + acc[4*t+2] * inv, 0.f);
        r.w = fmaxf(sk.w + acc[4*t+3] * inv, 0.f);
        op[t] = r;
    }
}

// ---------------- pooling ----------------
__global__ void pool_kernel(const float* __restrict__ h, const int* __restrict__ batch,
                            float* __restrict__ pool, int* __restrict__ pcnt)
{
    int i = blockIdx.x * blockDim.x + threadIdx.x;
    if (i >= N_NODES) return;
    int g = batch[i];
    atomicAdd(&pcnt[g], 1);
    const float4* hp = (const float4*)(h + (size_t)i * DCH);
    #pragma unroll
    for (int t = 0; t < 6; t++) {
        float4 f = hp[t];
        atomicAdd(&pool[g * DCH + 4*t],     f.x);
        atomicAdd(&pool[g * DCH + 4*t + 1], f.y);
        atomicAdd(&pool[g * DCH + 4*t + 2], f.z);
        atomicAdd(&pool[g * DCH + 4*t + 3], f.w);
    }
}

// ---------------- final MLP: one block per graph ----------------
__global__ __launch_bounds__(128) void mlp_kernel(
    const float* __restrict__ pool, const int* __restrict__ pcnt,
    const float* __restrict__ gf,
    const float* __restrict__ gfW1, const float* __restrict__ gfb1,
    const float* __restrict__ gfW2, const float* __restrict__ gfb2,
    const float* __restrict__ W1, const float* __restrict__ b1,
    const float* __restrict__ W2, const float* __restrict__ b2,
    const float* __restrict__ W3, const float* __restrict__ b3,
    float* __restrict__ out)
{
    int g = blockIdx.x;
    int t = threadIdx.x;
    __shared__ float z[36];
    __shared__ float g1[12];
    __shared__ float h1[128];
    __shared__ float h2[128];
    __shared__ float wsum[2];

    if (t < 12) {
        float a = gfb1[t];
        #pragma unroll
        for (int j = 0; j < 6; j++) a += gf[g * 6 + j] * gfW1[j * 12 + t];
        g1[t] = fmaxf(a, 0.f);
    }
    if (t < 24) {
        float c = fmaxf((float)pcnt[g], 1.f);
        z[t] = pool[g * DCH + t] / c;
    }
    __syncthreads();
    if (t < 12) {
        float a = gfb2[t];
        #pragma unroll
        for (int j = 0; j < 12; j++) a += g1[j] * gfW2[j * 12 + t];
        z[24 + t] = fmaxf(a, 0.f);
    }
    __syncthreads();
    {
        float a = b1[t];
        #pragma unroll
        for (int j = 0; j < 36; j++) a += z[j] * W1[j * 128 + t];
        h1[t] = fmaxf(a, 0.f);
    }
    __syncthreads();
    {
        float a = b2[t];
        for (int j = 0; j < 128; j++) a += h1[j] * W2[j * 128 + t];
        h2[t] = fmaxf(a, 0.f);
    }
    __syncthreads();
    float p = h2[t] * W3[t];
    for (int off = 32; off; off >>= 1) p += __shfl_down(p, off);
    if ((t & 63) == 0) wsum[t >> 6] = p;
    __syncthreads();
    if (t == 0) out[g] = wsum[0] + wsum[1] + b3[0];
}

// ---------------- launch ----------------
extern "C" void kernel_launch(void* const* d_in, const int* in_sizes, int n_in,
                              void* d_out, int out_size, void* d_ws, size_t ws_size,
                              hipStream_t stream)
{
    const float* x     = (const float*)d_in[0];
    const int*   ei    = (const int*)d_in[1];
    const int*   batch = (const int*)d_in[2];
    const float* gf    = (const float*)d_in[3];
    const float* Wq    = (const float*)d_in[4];
    const float* bq    = (const float*)d_in[5];
    const float* Wk    = (const float*)d_in[6];
    const float* bk    = (const float*)d_in[7];
    const float* Wv    = (const float*)d_in[8];
    const float* bv    = (const float*)d_in[9];
    const float* Ws    = (const float*)d_in[10];
    const float* bs    = (const float*)d_in[11];
    const float* gfW1  = (const float*)d_in[12];
    const float* gfb1  = (const float*)d_in[13];
    const float* gfW2  = (const float*)d_in[14];
    const float* gfb2  = (const float*)d_in[15];
    const float* W1    = (const float*)d_in[16];
    const float* b1    = (const float*)d_in[17];
    const float* W2    = (const float*)d_in[18];
    const float* b2    = (const float*)d_in[19];
    const float* W3    = (const float*)d_in[20];
    const float* b3    = (const float*)d_in[21];
    float* out = (float*)d_out;

    const int* esrc = ei;
    const int* edst = ei + N_EDGES;

    // workspace layout
    char* ws = (char*)d_ws;
    size_t off = 0;
    auto alloc = [&](size_t bytes) -> void* {
        void* p = ws + off;
        off = (off + bytes + 255) & ~(size_t)255;
        return p;
    };
    float* q    = (float*)alloc((size_t)N_NODES * DCH * 4);
    float* k    = (float*)alloc((size_t)N_NODES * DCH * 4);
    float* v    = (float*)alloc((size_t)N_NODES * DCH * 4);
    float* hA   = (float*)alloc((size_t)N_NODES * DCH * 4);
    float* hB   = (float*)alloc((size_t)N_NODES * DCH * 4);
    int* counts    = (int*)alloc((size_t)N_NODES * 4);
    int* row_start = (int*)alloc((size_t)N_NODES * 4);
    int* cursor    = (int*)alloc((size_t)N_NODES * 4);
    int* csr_src   = (int*)alloc((size_t)N_EDGES * 4);
    int* bsums     = (int*)alloc(1024);
    float* pool    = (float*)alloc((size_t)N_GRAPHS * DCH * 4);
    int* pcnt      = (int*)alloc((size_t)N_GRAPHS * 4);

    const int NB_NODE = (N_NODES + 255) / 256;
    const int NB_EDGE = (N_EDGES + 255) / 256;
    const int NB_SCAN = (N_NODES + 1023) / 1024;  // 98

    // ---- CSR build (deterministic structure; per call) ----
    hipMemsetAsync(counts, 0, (size_t)N_NODES * 4, stream);
    hipMemsetAsync(cursor, 0, (size_t)N_NODES * 4, stream);
    hist_kernel<<<NB_EDGE, 256, 0, stream>>>(edst, counts);
    scan1_kernel<<<NB_SCAN, 1024, 0, stream>>>(counts, row_start, bsums);
    scan2_kernel<<<1, 128, 0, stream>>>(bsums, NB_SCAN);
    scan3_kernel<<<NB_NODE, 256, 0, stream>>>(row_start, bsums);
    scatter_kernel<<<NB_EDGE, 256, 0, stream>>>(esrc, edst, row_start, cursor, csr_src);

    // ---- layers ----
    const float* hin = x;
    float* hbuf[2] = {hA, hB};
    for (int l = 0; l < NLAYERS; l++) {
        float* hout = hbuf[l & 1];
        lin_kernel<<<NB_NODE, 256, 0, stream>>>(
            hin, Wq + l * 576, bq + l * 24, Wk + l * 576, bk + l * 24,
            Wv + l * 576, bv + l * 24, Ws + l * 576, bs + l * 24,
            q, k, v, hout);
        attn_kernel<<<NB_NODE, 256, 0, stream>>>(
            q, k, v, hout, row_start, counts, csr_src, hout);
        hin = hout;
    }

    // ---- pooling + MLP ----
    hipMemsetAsync(pool, 0, (size_t)N_GRAPHS * DCH * 4, stream);
    hipMemsetAsync(pcnt, 0, (size_t)N_GRAPHS * 4, stream);
    pool_kernel<<<NB_NODE, 256, 0, stream>>>(hin, batch, pool, pcnt);
    mlp_kernel<<<N_GRAPHS, 128, 0, stream>>>(
        pool, pcnt, gf, gfW1, gfb1, gfW2, gfb2, W1, b1, W2, b2, W3, b3, out);
}

// Round 2
// 1034.960 us; speedup vs baseline: 1.4699x; 1.4699x over previous
//
#include <hip/hip_runtime.h>
#include <math.h>

#define N_NODES  100000
#define N_EDGES  3200000
#define N_GRAPHS 512
#define DCH      24
#define NLAYERS  4

// ---------------- linear kernel: q,k,v,skip = h @ W* + b* ----------------
__global__ __launch_bounds__(256) void lin_kernel(
    const float* __restrict__ h,
    const float* __restrict__ Wq, const float* __restrict__ bq,
    const float* __restrict__ Wk, const float* __restrict__ bk,
    const float* __restrict__ Wv, const float* __restrict__ bv,
    const float* __restrict__ Ws, const float* __restrict__ bs,
    float* __restrict__ q, float* __restrict__ k, float* __restrict__ v,
    float* __restrict__ skip)
{
    __shared__ float sW[4 * 576];
    __shared__ float sb[4 * 24];
    for (int i = threadIdx.x; i < 576; i += blockDim.x) {
        sW[0 * 576 + i] = Wq[i];
        sW[1 * 576 + i] = Wk[i];
        sW[2 * 576 + i] = Wv[i];
        sW[3 * 576 + i] = Ws[i];
    }
    if (threadIdx.x < 24) {
        sb[0 * 24 + threadIdx.x] = bq[threadIdx.x];
        sb[1 * 24 + threadIdx.x] = bk[threadIdx.x];
        sb[2 * 24 + threadIdx.x] = bv[threadIdx.x];
        sb[3 * 24 + threadIdx.x] = bs[threadIdx.x];
    }
    __syncthreads();

    int node = blockIdx.x * blockDim.x + threadIdx.x;
    if (node >= N_NODES) return;

    float hx[24];
    const float4* hp = (const float4*)(h + (size_t)node * DCH);
    #pragma unroll
    for (int t = 0; t < 6; t++) {
        float4 f = hp[t];
        hx[4*t] = f.x; hx[4*t+1] = f.y; hx[4*t+2] = f.z; hx[4*t+3] = f.w;
    }

    float* outs[4] = {q, k, v, skip};
    #pragma unroll
    for (int mtx = 0; mtx < 4; mtx++) {
        float o[24];
        #pragma unroll
        for (int c = 0; c < 24; c++) o[c] = sb[mtx * 24 + c];
        #pragma unroll
        for (int ci = 0; ci < 24; ci++) {
            float hv = hx[ci];
            #pragma unroll
            for (int c = 0; c < 24; c++)
                o[c] += hv * sW[mtx * 576 + ci * 24 + c];
        }
        float4* op = (float4*)(outs[mtx] + (size_t)node * DCH);
        #pragma unroll
        for (int t = 0; t < 6; t++) {
            float4 f;
            f.x = o[4*t]; f.y = o[4*t+1]; f.z = o[4*t+2]; f.w = o[4*t+3];
            op[t] = f;
        }
    }
}

// ---------------- CSR build ----------------
__global__ void hist_kernel(const int* __restrict__ dst, int* __restrict__ counts)
{
    int e = blockIdx.x * blockDim.x + threadIdx.x;
    if (e < N_EDGES) atomicAdd(&counts[dst[e]], 1);
}

__global__ __launch_bounds__(1024) void scan1_kernel(
    const int* __restrict__ counts, int* __restrict__ row_start, int* __restrict__ bsums)
{
    __shared__ int sd[1024];
    int gid = blockIdx.x * 1024 + threadIdx.x;
    int vin = (gid < N_NODES) ? counts[gid] : 0;
    sd[threadIdx.x] = vin;
    __syncthreads();
    for (int off = 1; off < 1024; off <<= 1) {
        int t = (threadIdx.x >= off) ? sd[threadIdx.x - off] : 0;
        __syncthreads();
        sd[threadIdx.x] += t;
        __syncthreads();
    }
    int incl = sd[threadIdx.x];
    if (gid < N_NODES) row_start[gid] = incl - vin;  // block-local exclusive
    if (threadIdx.x == 1023) bsums[blockIdx.x] = incl;
}

__global__ __launch_bounds__(128) void scan2_kernel(int* __restrict__ bsums, int nb)
{
    __shared__ int sd[128];
    int v = (threadIdx.x < nb) ? bsums[threadIdx.x] : 0;
    sd[threadIdx.x] = v;
    __syncthreads();
    for (int off = 1; off < 128; off <<= 1) {
        int t = (threadIdx.x >= off) ? sd[threadIdx.x - off] : 0;
        __syncthreads();
        sd[threadIdx.x] += t;
        __syncthreads();
    }
    if (threadIdx.x < nb) bsums[threadIdx.x] = sd[threadIdx.x] - v;  // exclusive
}

__global__ void scan3_kernel(int* __restrict__ row_start, const int* __restrict__ bsums)
{
    int gid = blockIdx.x * blockDim.x + threadIdx.x;
    if (gid < N_NODES) row_start[gid] += bsums[gid >> 10];
}

__global__ void scatter_kernel(
    const int* __restrict__ src, const int* __restrict__ dst,
    const int* __restrict__ row_start, int* __restrict__ cursor,
    int* __restrict__ csr_src)
{
    int e = blockIdx.x * blockDim.x + threadIdx.x;
    if (e < N_EDGES) {
        int d = dst[e];
        int pos = row_start[d] + atomicAdd(&cursor[d], 1);
        csr_src[pos] = src[e];
    }
}

// ---------------- attention: 8 lanes per dst node, online softmax ----------------
#define LPN 8  // lanes per node
__global__ __launch_bounds__(256) void attn_kernel(
    const float* __restrict__ q, const float* __restrict__ k, const float* __restrict__ v,
    const float* __restrict__ skip,
    const int* __restrict__ row_start, const int* __restrict__ counts,
    const int* __restrict__ csr_src,
    float* __restrict__ out)
{
    int i   = blockIdx.x * (256 / LPN) + (threadIdx.x >> 3);
    int sub = threadIdx.x & (LPN - 1);
    if (i >= N_NODES) return;

    float qr[24];
    const float4* qp = (const float4*)(q + (size_t)i * DCH);
    #pragma unroll
    for (int t = 0; t < 6; t++) {
        float4 f = qp[t];
        qr[4*t] = f.x; qr[4*t+1] = f.y; qr[4*t+2] = f.z; qr[4*t+3] = f.w;
    }

    float m = -INFINITY, s = 0.f;
    float acc[24];
    #pragma unroll
    for (int c = 0; c < 24; c++) acc[c] = 0.f;

    int beg = row_start[i];
    int cnt = counts[i];
    const float scale = 0.2041241452319315f;  // 1/sqrt(24)

    int src_next = (sub < cnt) ? csr_src[beg + sub] : 0;
    for (int e = sub; e < cnt; e += LPN) {
        int src = src_next;
        int en = e + LPN;
        src_next = (en < cnt) ? csr_src[beg + en] : 0;

        const float4* kp = (const float4*)(k + (size_t)src * DCH);
        const float4* vp = (const float4*)(v + (size_t)src * DCH);
        float4 kk[6], vv[6];
        #pragma unroll
        for (int t = 0; t < 6; t++) kk[t] = kp[t];
        #pragma unroll
        for (int t = 0; t < 6; t++) vv[t] = vp[t];

        float dot = 0.f;
        #pragma unroll
        for (int t = 0; t < 6; t++)
            dot += qr[4*t]*kk[t].x + qr[4*t+1]*kk[t].y + qr[4*t+2]*kk[t].z + qr[4*t+3]*kk[t].w;
        dot *= scale;

        if (dot > m) {
            float sc = __expf(m - dot);   // first iter: exp(-inf) = 0
            s = s * sc + 1.f;
            #pragma unroll
            for (int t = 0; t < 6; t++) {
                acc[4*t]   = acc[4*t]   * sc + vv[t].x;
                acc[4*t+1] = acc[4*t+1] * sc + vv[t].y;
                acc[4*t+2] = acc[4*t+2] * sc + vv[t].z;
                acc[4*t+3] = acc[4*t+3] * sc + vv[t].w;
            }
            m = dot;
        } else {
            float w = __expf(dot - m);
            s += w;
            #pragma unroll
            for (int t = 0; t < 6; t++) {
                acc[4*t]   += w * vv[t].x;
                acc[4*t+1] += w * vv[t].y;
                acc[4*t+2] += w * vv[t].z;
                acc[4*t+3] += w * vv[t].w;
            }
        }
    }

    // merge the LPN lanes' online-softmax states (butterfly within the 8-lane group)
    #pragma unroll
    for (int off = 1; off < LPN; off <<= 1) {
        float m2 = __shfl_xor(m, off);
        float s2 = __shfl_xor(s, off);
        float mn = fmaxf(m, m2);
        float w1 = (m  == mn) ? 1.f : __expf(m  - mn);  // avoids (-inf)-(-inf)=NaN
        float w2 = (m2 == mn) ? 1.f : __expf(m2 - mn);
        s = s * w1 + s2 * w2;
        #pragma unroll
        for (int c = 0; c < 24; c++) {
            float a2 = __shfl_xor(acc[c], off);
            acc[c] = acc[c] * w1 + a2 * w2;
        }
        m = mn;
    }

    if (sub == 0) {
        float inv = 1.f / (s + 1e-16f);
        const float4* sp = (const float4*)(skip + (size_t)i * DCH);
        float4* op = (float4*)(out + (size_t)i * DCH);
        #pragma unroll
        for (int t = 0; t < 6; t++) {
            float4 sk = sp[t];
            float4 r;
            r.x = fmaxf(sk.x + acc[4*t]   * inv, 0.f);
            r.y = fmaxf(sk.y + acc[4*t+1] * inv, 0.f);
            r.z = fmaxf(sk.z + acc[4*t+2] * inv, 0.f);
            r.w = fmaxf(sk.w + acc[4*t+3] * inv, 0.f);
            op[t] = r;
        }
    }
}

// ---------------- pooling: wave-reduce + LDS slots, few global atomics ----------------
__global__ __launch_bounds__(256) void pool_kernel(
    const float* __restrict__ h, const int* __restrict__ batch,
    float* __restrict__ pool, float* __restrict__ pcnt)
{
    __shared__ float sp[16][25];  // [slot][0..23 = channels, 24 = count]
    for (int t = threadIdx.x; t < 16 * 25; t += 256) ((float*)sp)[t] = 0.f;
    __syncthreads();

    int base = blockIdx.x * 256;
    int g0 = batch[base];
    int i = base + threadIdx.x;
    bool valid = (i < N_NODES);
    int g = valid ? batch[i] : -1;

    float hx[24];
    if (valid) {
        const float4* hp = (const float4*)(h + (size_t)i * DCH);
        #pragma unroll
        for (int t = 0; t < 6; t++) {
            float4 f = hp[t];
            hx[4*t] = f.x; hx[4*t+1] = f.y; hx[4*t+2] = f.z; hx[4*t+3] = f.w;
        }
    } else {
        #pragma unroll
        for (int c = 0; c < 24; c++) hx[c] = 0.f;
    }

    int gfirst = __shfl(g, 0);
    bool uniform = __all(valid && (g == gfirst));
    if (uniform) {
        // full-wave butterfly reduce of all 24 channels
        #pragma unroll
        for (int off = 1; off < 64; off <<= 1) {
            #pragma unroll
            for (int c = 0; c < 24; c++) hx[c] += __shfl_xor(hx[c], off);
        }
        if ((threadIdx.x & 63) == 0) {
            int rel = g - g0;  // 0..15 (block spans few graphs; batch sorted)
            if (rel < 16) {
                #pragma unroll
                for (int c = 0; c < 24; c++) atomicAdd(&sp[rel][c], hx[c]);
                atomicAdd(&sp[rel][24], 64.f);
            } else {
                #pragma unroll
                for (int c = 0; c < 24; c++) atomicAdd(&pool[g * DCH + c], hx[c]);
                atomicAdd(&pcnt[g], 64.f);
            }
        }
    } else if (valid) {
        int rel = g - g0;
        if (rel < 16) {
            #pragma unroll
            for (int c = 0; c < 24; c++) atomicAdd(&sp[rel][c], hx[c]);
            atomicAdd(&sp[rel][24], 1.f);
        } else {
            #pragma unroll
            for (int c = 0; c < 24; c++) atomicAdd(&pool[g * DCH + c], hx[c]);
            atomicAdd(&pcnt[g], 1.f);
        }
    }
    __syncthreads();

    // flush nonzero slots
    for (int t = threadIdx.x; t < 16 * 25; t += 256) {
        int slot = t / 25, c = t % 25;
        float val = sp[slot][c];
        if (val != 0.f) {
            int g2 = g0 + slot;
            if (c < 24) atomicAdd(&pool[g2 * DCH + c], val);
            else        atomicAdd(&pcnt[g2], val);
        }
    }
}

// ---------------- final MLP: one block per graph ----------------
__global__ __launch_bounds__(128) void mlp_kernel(
    const float* __restrict__ pool, const float* __restrict__ pcnt,
    const float* __restrict__ gf,
    const float* __restrict__ gfW1, const float* __restrict__ gfb1,
    const float* __restrict__ gfW2, const float* __restrict__ gfb2,
    const float* __restrict__ W1, const float* __restrict__ b1,
    const float* __restrict__ W2, const float* __restrict__ b2,
    const float* __restrict__ W3, const float* __restrict__ b3,
    float* __restrict__ out)
{
    int g = blockIdx.x;
    int t = threadIdx.x;
    __shared__ float z[36];
    __shared__ float g1[12];
    __shared__ float h1[128];
    __shared__ float h2[128];
    __shared__ float wsum[2];

    if (t < 12) {
        float a = gfb1[t];
        #pragma unroll
        for (int j = 0; j < 6; j++) a += gf[g * 6 + j] * gfW1[j * 12 + t];
        g1[t] = fmaxf(a, 0.f);
    }
    if (t < 24) {
        float c = fmaxf(pcnt[g], 1.f);
        z[t] = pool[g * DCH + t] / c;
    }
    __syncthreads();
    if (t < 12) {
        float a = gfb2[t];
        #pragma unroll
        for (int j = 0; j < 12; j++) a += g1[j] * gfW2[j * 12 + t];
        z[24 + t] = fmaxf(a, 0.f);
    }
    __syncthreads();
    {
        float a = b1[t];
        #pragma unroll
        for (int j = 0; j < 36; j++) a += z[j] * W1[j * 128 + t];
        h1[t] = fmaxf(a, 0.f);
    }
    __syncthreads();
    {
        float a = b2[t];
        for (int j = 0; j < 128; j++) a += h1[j] * W2[j * 128 + t];
        h2[t] = fmaxf(a, 0.f);
    }
    __syncthreads();
    float p = h2[t] * W3[t];
    for (int off = 32; off; off >>= 1) p += __shfl_down(p, off);
    if ((t & 63) == 0) wsum[t >> 6] = p;
    __syncthreads();
    if (t == 0) out[g] = wsum[0] + wsum[1] + b3[0];
}

// ---------------- launch ----------------
extern "C" void kernel_launch(void* const* d_in, const int* in_sizes, int n_in,
                              void* d_out, int out_size, void* d_ws, size_t ws_size,
                              hipStream_t stream)
{
    const float* x     = (const float*)d_in[0];
    const int*   ei    = (const int*)d_in[1];
    const int*   batch = (const int*)d_in[2];
    const float* gf    = (const float*)d_in[3];
    const float* Wq    = (const float*)d_in[4];
    const float* bq    = (const float*)d_in[5];
    const float* Wk    = (const float*)d_in[6];
    const float* bk    = (const float*)d_in[7];
    const float* Wv    = (const float*)d_in[8];
    const float* bv    = (const float*)d_in[9];
    const float* Ws    = (const float*)d_in[10];
    const float* bs    = (const float*)d_in[11];
    const float* gfW1  = (const float*)d_in[12];
    const float* gfb1  = (const float*)d_in[13];
    const float* gfW2  = (const float*)d_in[14];
    const float* gfb2  = (const float*)d_in[15];
    const float* W1    = (const float*)d_in[16];
    const float* b1    = (const float*)d_in[17];
    const float* W2    = (const float*)d_in[18];
    const float* b2    = (const float*)d_in[19];
    const float* W3    = (const float*)d_in[20];
    const float* b3    = (const float*)d_in[21];
    float* out = (float*)d_out;

    const int* esrc = ei;
    const int* edst = ei + N_EDGES;

    // workspace layout
    char* ws = (char*)d_ws;
    size_t off = 0;
    auto alloc = [&](size_t bytes) -> void* {
        void* p = ws + off;
        off = (off + bytes + 255) & ~(size_t)255;
        return p;
    };
    float* q    = (float*)alloc((size_t)N_NODES * DCH * 4);
    float* k    = (float*)alloc((size_t)N_NODES * DCH * 4);
    float* v    = (float*)alloc((size_t)N_NODES * DCH * 4);
    float* hA   = (float*)alloc((size_t)N_NODES * DCH * 4);
    float* hB   = (float*)alloc((size_t)N_NODES * DCH * 4);
    int* counts    = (int*)alloc((size_t)N_NODES * 4);
    int* row_start = (int*)alloc((size_t)N_NODES * 4);
    int* cursor    = (int*)alloc((size_t)N_NODES * 4);
    int* csr_src   = (int*)alloc((size_t)N_EDGES * 4);
    int* bsums     = (int*)alloc(1024);
    float* pool    = (float*)alloc((size_t)N_GRAPHS * DCH * 4);
    float* pcnt    = (float*)alloc((size_t)N_GRAPHS * 4);

    const int NB_NODE = (N_NODES + 255) / 256;
    const int NB_EDGE = (N_EDGES + 255) / 256;
    const int NB_SCAN = (N_NODES + 1023) / 1024;  // 98
    const int NB_ATTN = (N_NODES * LPN + 255) / 256;

    // ---- CSR build (structure only; once per call) ----
    hipMemsetAsync(counts, 0, (size_t)N_NODES * 4, stream);
    hipMemsetAsync(cursor, 0, (size_t)N_NODES * 4, stream);
    hist_kernel<<<NB_EDGE, 256, 0, stream>>>(edst, counts);
    scan1_kernel<<<NB_SCAN, 1024, 0, stream>>>(counts, row_start, bsums);
    scan2_kernel<<<1, 128, 0, stream>>>(bsums, NB_SCAN);
    scan3_kernel<<<NB_NODE, 256, 0, stream>>>(row_start, bsums);
    scatter_kernel<<<NB_EDGE, 256, 0, stream>>>(esrc, edst, row_start, cursor, csr_src);

    // ---- layers ----
    const float* hin = x;
    float* hbuf[2] = {hA, hB};
    for (int l = 0; l < NLAYERS; l++) {
        float* hout = hbuf[l & 1];
        lin_kernel<<<NB_NODE, 256, 0, stream>>>(
            hin, Wq + l * 576, bq + l * 24, Wk + l * 576, bk + l * 24,
            Wv + l * 576, bv + l * 24, Ws + l * 576, bs + l * 24,
            q, k, v, hout);
        attn_kernel<<<NB_ATTN, 256, 0, stream>>>(
            q, k, v, hout, row_start, counts, csr_src, hout);
        hin = hout;
    }

    // ---- pooling + MLP ----
    hipMemsetAsync(pool, 0, (size_t)N_GRAPHS * DCH * 4, stream);
    hipMemsetAsync(pcnt, 0, (size_t)N_GRAPHS * 4, stream);
    pool_kernel<<<NB_NODE, 256, 0, stream>>>(hin, batch, pool, pcnt);
    mlp_kernel<<<N_GRAPHS, 128, 0, stream>>>(
        pool, pcnt, gf, gfW1, gfb1, gfW2, gfb2, W1, b1, W2, b2, W3, b3, out);
}

// Round 3
// 628.504 us; speedup vs baseline: 2.4205x; 1.6467x over previous
//
#include <hip/hip_runtime.h>
#include <math.h>

#define N_NODES  100000
#define N_EDGES  3200000
#define N_GRAPHS 512
#define DCH      24
#define NLAYERS  4

#define NBINS    782      // ceil(N_NODES / 128)
#define NBINS_P  800
#define EPB      16000    // edges per partition block (N_EDGES / 200)
#define NB_PART  200

// ---------------- linear kernel: q, kv(packed), skip ----------------
__global__ __launch_bounds__(256) void lin_kernel(
    const float* __restrict__ h,
    const float* __restrict__ Wq, const float* __restrict__ bq,
    const float* __restrict__ Wk, const float* __restrict__ bk,
    const float* __restrict__ Wv, const float* __restrict__ bv,
    const float* __restrict__ Ws, const float* __restrict__ bs,
    float* __restrict__ q, float* __restrict__ kv, float* __restrict__ skip)
{
    __shared__ float sW[4 * 576];
    __shared__ float sb[4 * 24];
    for (int i = threadIdx.x; i < 576; i += blockDim.x) {
        sW[0 * 576 + i] = Wq[i];
        sW[1 * 576 + i] = Wk[i];
        sW[2 * 576 + i] = Wv[i];
        sW[3 * 576 + i] = Ws[i];
    }
    if (threadIdx.x < 24) {
        sb[0 * 24 + threadIdx.x] = bq[threadIdx.x];
        sb[1 * 24 + threadIdx.x] = bk[threadIdx.x];
        sb[2 * 24 + threadIdx.x] = bv[threadIdx.x];
        sb[3 * 24 + threadIdx.x] = bs[threadIdx.x];
    }
    __syncthreads();

    int node = blockIdx.x * blockDim.x + threadIdx.x;
    if (node >= N_NODES) return;

    float hx[24];
    const float4* hp = (const float4*)(h + (size_t)node * DCH);
    #pragma unroll
    for (int t = 0; t < 6; t++) {
        float4 f = hp[t];
        hx[4*t] = f.x; hx[4*t+1] = f.y; hx[4*t+2] = f.z; hx[4*t+3] = f.w;
    }

    float* dsts[4] = {
        q + (size_t)node * DCH,
        kv + (size_t)node * 64,          // k
        kv + (size_t)node * 64 + 24,     // v
        skip + (size_t)node * DCH
    };
    #pragma unroll
    for (int mtx = 0; mtx < 4; mtx++) {
        float o[24];
        #pragma unroll
        for (int c = 0; c < 24; c++) o[c] = sb[mtx * 24 + c];
        #pragma unroll
        for (int ci = 0; ci < 24; ci++) {
            float hv = hx[ci];
            #pragma unroll
            for (int c = 0; c < 24; c++)
                o[c] += hv * sW[mtx * 576 + ci * 24 + c];
        }
        float4* op = (float4*)dsts[mtx];
        #pragma unroll
        for (int t = 0; t < 6; t++) {
            float4 f;
            f.x = o[4*t]; f.y = o[4*t+1]; f.z = o[4*t+2]; f.w = o[4*t+3];
            op[t] = f;
        }
    }
}

// ---------------- CSR build: 2-level bucket sort ----------------
__global__ __launch_bounds__(512) void bin_hist_kernel(
    const int* __restrict__ edst, int* __restrict__ bin_counts)
{
    __shared__ int hist[NBINS_P];
    for (int t = threadIdx.x; t < NBINS_P; t += 512) hist[t] = 0;
    __syncthreads();
    int e0 = blockIdx.x * EPB;
    int e1 = min(e0 + EPB, N_EDGES);
    for (int e = e0 + threadIdx.x; e < e1; e += 512)
        atomicAdd(&hist[edst[e] >> 7], 1);
    __syncthreads();
    for (int t = threadIdx.x; t < NBINS; t += 512)
        if (hist[t]) atomicAdd(&bin_counts[t], hist[t]);
}

__global__ __launch_bounds__(1024) void bin_scan_kernel(
    const int* __restrict__ bin_counts,
    int* __restrict__ bin_base, int* __restrict__ bin_cursor,
    int* __restrict__ row_start)
{
    __shared__ int sd[1024];
    int t = threadIdx.x;
    int v = (t < NBINS) ? bin_counts[t] : 0;
    sd[t] = v;
    __syncthreads();
    for (int off = 1; off < 1024; off <<= 1) {
        int u = (t >= off) ? sd[t - off] : 0;
        __syncthreads();
        sd[t] += u;
        __syncthreads();
    }
    int ex = sd[t] - v;
    if (t < NBINS) { bin_base[t] = ex; bin_cursor[t] = ex; }
    if (t == 0) { bin_base[NBINS] = N_EDGES; row_start[N_NODES] = N_EDGES; }
}

__global__ __launch_bounds__(512) void partition_kernel(
    const int* __restrict__ esrc, const int* __restrict__ edst,
    int* __restrict__ bin_cursor, unsigned int* __restrict__ bucket)
{
    __shared__ int hist[NBINS_P];
    __shared__ int base[NBINS_P];
    for (int t = threadIdx.x; t < NBINS_P; t += 512) hist[t] = 0;
    __syncthreads();
    int e0 = blockIdx.x * EPB;
    int e1 = min(e0 + EPB, N_EDGES);
    for (int e = e0 + threadIdx.x; e < e1; e += 512)
        atomicAdd(&hist[edst[e] >> 7], 1);
    __syncthreads();
    for (int t = threadIdx.x; t < NBINS; t += 512) {
        int hcount = hist[t];
        base[t] = hcount ? atomicAdd(&bin_cursor[t], hcount) : 0;
    }
    __syncthreads();
    for (int t = threadIdx.x; t < NBINS_P; t += 512) hist[t] = 0;
    __syncthreads();
    for (int e = e0 + threadIdx.x; e < e1; e += 512) {
        int d = edst[e];
        int b = d >> 7;
        int lc = atomicAdd(&hist[b], 1);
        bucket[base[b] + lc] = ((unsigned)(d & 127) << 17) | (unsigned)esrc[e];
    }
}

__global__ __launch_bounds__(256) void bin_scatter_kernel(
    const unsigned int* __restrict__ bucket, const int* __restrict__ bin_base,
    int* __restrict__ row_start, int* __restrict__ csr_src)
{
    int b = blockIdx.x;
    int node0 = b << 7;
    int nn = min(128, N_NODES - node0);
    int ebeg = bin_base[b], eend = bin_base[b + 1];
    __shared__ int c0[128], s[128], cur[128];
    int tid = threadIdx.x;
    if (tid < 128) c0[tid] = 0;
    __syncthreads();
    for (int i = ebeg + tid; i < eend; i += 256)
        atomicAdd(&c0[bucket[i] >> 17], 1);
    __syncthreads();
    if (tid < 128) s[tid] = c0[tid];
    __syncthreads();
    for (int off = 1; off < 128; off <<= 1) {
        int u = (tid < 128 && tid >= off) ? s[tid - off] : 0;
        __syncthreads();
        if (tid < 128) s[tid] += u;
        __syncthreads();
    }
    if (tid < nn) {
        int ex = ebeg + s[tid] - c0[tid];
        row_start[node0 + tid] = ex;
        cur[tid] = ex;
    }
    __syncthreads();
    for (int i = ebeg + tid; i < eend; i += 256) {
        unsigned p = bucket[i];
        int j = p >> 17;
        int pos = atomicAdd(&cur[j], 1);
        csr_src[pos] = (int)(p & 0x1FFFF);
    }
}

// ---------------- attention: 8 lanes per dst node, online softmax ----------------
#define LPN 8  // lanes per node
__global__ __launch_bounds__(256) void attn_kernel(
    const float* __restrict__ q, const float* __restrict__ kv,
    const float* __restrict__ skip,
    const int* __restrict__ row_start,
    const int* __restrict__ csr_src,
    float* __restrict__ out)
{
    int i   = blockIdx.x * (256 / LPN) + (threadIdx.x >> 3);
    int sub = threadIdx.x & (LPN - 1);
    if (i >= N_NODES) return;

    float qr[24];
    const float4* qp = (const float4*)(q + (size_t)i * DCH);
    #pragma unroll
    for (int t = 0; t < 6; t++) {
        float4 f = qp[t];
        qr[4*t] = f.x; qr[4*t+1] = f.y; qr[4*t+2] = f.z; qr[4*t+3] = f.w;
    }

    float m = -INFINITY, s = 0.f;
    float acc[24];
    #pragma unroll
    for (int c = 0; c < 24; c++) acc[c] = 0.f;

    int beg = row_start[i];
    int cnt = row_start[i + 1] - beg;
    const float scale = 0.2041241452319315f;  // 1/sqrt(24)

    int src_next = (sub < cnt) ? csr_src[beg + sub] : 0;
    for (int e = sub; e < cnt; e += LPN) {
        int src = src_next;
        int en = e + LPN;
        src_next = (en < cnt) ? csr_src[beg + en] : 0;

        const float4* kvp = (const float4*)(kv + (size_t)src * 64);
        float4 kk[6], vv[6];
        #pragma unroll
        for (int t = 0; t < 6; t++) kk[t] = kvp[t];
        #pragma unroll
        for (int t = 0; t < 6; t++) vv[t] = kvp[6 + t];

        float dot = 0.f;
        #pragma unroll
        for (int t = 0; t < 6; t++)
            dot += qr[4*t]*kk[t].x + qr[4*t+1]*kk[t].y + qr[4*t+2]*kk[t].z + qr[4*t+3]*kk[t].w;
        dot *= scale;

        if (dot > m) {
            float sc = __expf(m - dot);   // first iter: exp(-inf) = 0
            s = s * sc + 1.f;
            #pragma unroll
            for (int t = 0; t < 6; t++) {
                acc[4*t]   = acc[4*t]   * sc + vv[t].x;
                acc[4*t+1] = acc[4*t+1] * sc + vv[t].y;
                acc[4*t+2] = acc[4*t+2] * sc + vv[t].z;
                acc[4*t+3] = acc[4*t+3] * sc + vv[t].w;
            }
            m = dot;
        } else {
            float w = __expf(dot - m);
            s += w;
            #pragma unroll
            for (int t = 0; t < 6; t++) {
                acc[4*t]   += w * vv[t].x;
                acc[4*t+1] += w * vv[t].y;
                acc[4*t+2] += w * vv[t].z;
                acc[4*t+3] += w * vv[t].w;
            }
        }
    }

    // merge the LPN lanes' online-softmax states (butterfly within the 8-lane group)
    #pragma unroll
    for (int off = 1; off < LPN; off <<= 1) {
        float m2 = __shfl_xor(m, off);
        float s2 = __shfl_xor(s, off);
        float mn = fmaxf(m, m2);
        float w1 = (m  == mn) ? 1.f : __expf(m  - mn);  // avoids (-inf)-(-inf)=NaN
        float w2 = (m2 == mn) ? 1.f : __expf(m2 - mn);
        s = s * w1 + s2 * w2;
        #pragma unroll
        for (int c = 0; c < 24; c++) {
            float a2 = __shfl_xor(acc[c], off);
            acc[c] = acc[c] * w1 + a2 * w2;
        }
        m = mn;
    }

    if (sub == 0) {
        float inv = 1.f / (s + 1e-16f);
        const float4* sp = (const float4*)(skip + (size_t)i * DCH);
        float4* op = (float4*)(out + (size_t)i * DCH);
        #pragma unroll
        for (int t = 0; t < 6; t++) {
            float4 sk = sp[t];
            float4 r;
            r.x = fmaxf(sk.x + acc[4*t]   * inv, 0.f);
            r.y = fmaxf(sk.y + acc[4*t+1] * inv, 0.f);
            r.z = fmaxf(sk.z + acc[4*t+2] * inv, 0.f);
            r.w = fmaxf(sk.w + acc[4*t+3] * inv, 0.f);
            op[t] = r;
        }
    }
}

// ---------------- pooling: wave-reduce + LDS slots, few global atomics ----------------
__global__ __launch_bounds__(256) void pool_kernel(
    const float* __restrict__ h, const int* __restrict__ batch,
    float* __restrict__ pool, float* __restrict__ pcnt)
{
    __shared__ float sp[16][25];  // [slot][0..23 = channels, 24 = count]
    for (int t = threadIdx.x; t < 16 * 25; t += 256) ((float*)sp)[t] = 0.f;
    __syncthreads();

    int base = blockIdx.x * 256;
    int g0 = batch[base];
    int i = base + threadIdx.x;
    bool valid = (i < N_NODES);
    int g = valid ? batch[i] : -1;

    float hx[24];
    if (valid) {
        const float4* hp = (const float4*)(h + (size_t)i * DCH);
        #pragma unroll
        for (int t = 0; t < 6; t++) {
            float4 f = hp[t];
            hx[4*t] = f.x; hx[4*t+1] = f.y; hx[4*t+2] = f.z; hx[4*t+3] = f.w;
        }
    } else {
        #pragma unroll
        for (int c = 0; c < 24; c++) hx[c] = 0.f;
    }

    int gfirst = __shfl(g, 0);
    bool uniform = __all(valid && (g == gfirst));
    if (uniform) {
        #pragma unroll
        for (int off = 1; off < 64; off <<= 1) {
            #pragma unroll
            for (int c = 0; c < 24; c++) hx[c] += __shfl_xor(hx[c], off);
        }
        if ((threadIdx.x & 63) == 0) {
            int rel = g - g0;
            if (rel < 16) {
                #pragma unroll
                for (int c = 0; c < 24; c++) atomicAdd(&sp[rel][c], hx[c]);
                atomicAdd(&sp[rel][24], 64.f);
            } else {
                #pragma unroll
                for (int c = 0; c < 24; c++) atomicAdd(&pool[g * DCH + c], hx[c]);
                atomicAdd(&pcnt[g], 64.f);
            }
        }
    } else if (valid) {
        int rel = g - g0;
        if (rel < 16) {
            #pragma unroll
            for (int c = 0; c < 24; c++) atomicAdd(&sp[rel][c], hx[c]);
            atomicAdd(&sp[rel][24], 1.f);
        } else {
            #pragma unroll
            for (int c = 0; c < 24; c++) atomicAdd(&pool[g * DCH + c], hx[c]);
            atomicAdd(&pcnt[g], 1.f);
        }
    }
    __syncthreads();

    for (int t = threadIdx.x; t < 16 * 25; t += 256) {
        int slot = t / 25, c = t % 25;
        float val = sp[slot][c];
        if (val != 0.f) {
            int g2 = g0 + slot;
            if (c < 24) atomicAdd(&pool[g2 * DCH + c], val);
            else        atomicAdd(&pcnt[g2], val);
        }
    }
}

// ---------------- final MLP: one block per graph ----------------
__global__ __launch_bounds__(128) void mlp_kernel(
    const float* __restrict__ pool, const float* __restrict__ pcnt,
    const float* __restrict__ gf,
    const float* __restrict__ gfW1, const float* __restrict__ gfb1,
    const float* __restrict__ gfW2, const float* __restrict__ gfb2,
    const float* __restrict__ W1, const float* __restrict__ b1,
    const float* __restrict__ W2, const float* __restrict__ b2,
    const float* __restrict__ W3, const float* __restrict__ b3,
    float* __restrict__ out)
{
    int g = blockIdx.x;
    int t = threadIdx.x;
    __shared__ float z[36];
    __shared__ float g1[12];
    __shared__ float h1[128];
    __shared__ float h2[128];
    __shared__ float wsum[2];

    if (t < 12) {
        float a = gfb1[t];
        #pragma unroll
        for (int j = 0; j < 6; j++) a += gf[g * 6 + j] * gfW1[j * 12 + t];
        g1[t] = fmaxf(a, 0.f);
    }
    if (t < 24) {
        float c = fmaxf(pcnt[g], 1.f);
        z[t] = pool[g * DCH + t] / c;
    }
    __syncthreads();
    if (t < 12) {
        float a = gfb2[t];
        #pragma unroll
        for (int j = 0; j < 12; j++) a += g1[j] * gfW2[j * 12 + t];
        z[24 + t] = fmaxf(a, 0.f);
    }
    __syncthreads();
    {
        float a = b1[t];
        #pragma unroll
        for (int j = 0; j < 36; j++) a += z[j] * W1[j * 128 + t];
        h1[t] = fmaxf(a, 0.f);
    }
    __syncthreads();
    {
        float a = b2[t];
        for (int j = 0; j < 128; j++) a += h1[j] * W2[j * 128 + t];
        h2[t] = fmaxf(a, 0.f);
    }
    __syncthreads();
    float p = h2[t] * W3[t];
    for (int off = 32; off; off >>= 1) p += __shfl_down(p, off);
    if ((t & 63) == 0) wsum[t >> 6] = p;
    __syncthreads();
    if (t == 0) out[g] = wsum[0] + wsum[1] + b3[0];
}

// ---------------- launch ----------------
extern "C" void kernel_launch(void* const* d_in, const int* in_sizes, int n_in,
                              void* d_out, int out_size, void* d_ws, size_t ws_size,
                              hipStream_t stream)
{
    const float* x     = (const float*)d_in[0];
    const int*   ei    = (const int*)d_in[1];
    const int*   batch = (const int*)d_in[2];
    const float* gf    = (const float*)d_in[3];
    const float* Wq    = (const float*)d_in[4];
    const float* bq    = (const float*)d_in[5];
    const float* Wk    = (const float*)d_in[6];
    const float* bk    = (const float*)d_in[7];
    const float* Wv    = (const float*)d_in[8];
    const float* bv    = (const float*)d_in[9];
    const float* Ws    = (const float*)d_in[10];
    const float* bs    = (const float*)d_in[11];
    const float* gfW1  = (const float*)d_in[12];
    const float* gfb1  = (const float*)d_in[13];
    const float* gfW2  = (const float*)d_in[14];
    const float* gfb2  = (const float*)d_in[15];
    const float* W1    = (const float*)d_in[16];
    const float* b1    = (const float*)d_in[17];
    const float* W2    = (const float*)d_in[18];
    const float* b2    = (const float*)d_in[19];
    const float* W3    = (const float*)d_in[20];
    const float* b3    = (const float*)d_in[21];
    float* out = (float*)d_out;

    const int* esrc = ei;
    const int* edst = ei + N_EDGES;

    // workspace layout
    char* ws = (char*)d_ws;
    size_t off = 0;
    auto alloc = [&](size_t bytes) -> void* {
        void* p = ws + off;
        off = (off + bytes + 255) & ~(size_t)255;
        return p;
    };
    float* q    = (float*)alloc((size_t)N_NODES * DCH * 4);
    float* kv   = (float*)alloc((size_t)N_NODES * 64 * 4);
    float* hA   = (float*)alloc((size_t)N_NODES * DCH * 4);
    float* hB   = (float*)alloc((size_t)N_NODES * DCH * 4);
    int* row_start   = (int*)alloc(((size_t)N_NODES + 1) * 4);
    int* csr_src     = (int*)alloc((size_t)N_EDGES * 4);
    unsigned int* bucket = (unsigned int*)alloc((size_t)N_EDGES * 4);
    int* bin_counts  = (int*)alloc((size_t)NBINS_P * 4);
    int* bin_base    = (int*)alloc((size_t)(NBINS + 1) * 4);
    int* bin_cursor  = (int*)alloc((size_t)NBINS_P * 4);
    float* pool      = (float*)alloc((size_t)N_GRAPHS * DCH * 4);
    float* pcnt      = (float*)alloc((size_t)N_GRAPHS * 4);

    const int NB_NODE = (N_NODES + 255) / 256;
    const int NB_ATTN = (N_NODES * LPN + 255) / 256;

    // ---- CSR build: 2-level bucket sort ----
    hipMemsetAsync(bin_counts, 0, (size_t)NBINS_P * 4, stream);
    bin_hist_kernel<<<NB_PART, 512, 0, stream>>>(edst, bin_counts);
    bin_scan_kernel<<<1, 1024, 0, stream>>>(bin_counts, bin_base, bin_cursor, row_start);
    partition_kernel<<<NB_PART, 512, 0, stream>>>(esrc, edst, bin_cursor, bucket);
    bin_scatter_kernel<<<NBINS, 256, 0, stream>>>(bucket, bin_base, row_start, csr_src);

    // ---- layers ----
    const float* hin = x;
    float* hbuf[2] = {hA, hB};
    for (int l = 0; l < NLAYERS; l++) {
        float* hout = hbuf[l & 1];
        lin_kernel<<<NB_NODE, 256, 0, stream>>>(
            hin, Wq + l * 576, bq + l * 24, Wk + l * 576, bk + l * 24,
            Wv + l * 576, bv + l * 24, Ws + l * 576, bs + l * 24,
            q, kv, hout);
        attn_kernel<<<NB_ATTN, 256, 0, stream>>>(
            q, kv, hout, row_start, csr_src, hout);
        hin = hout;
    }

    // ---- pooling + MLP ----
    hipMemsetAsync(pool, 0, (size_t)N_GRAPHS * DCH * 4, stream);
    hipMemsetAsync(pcnt, 0, (size_t)N_GRAPHS * 4, stream);
    pool_kernel<<<NB_NODE, 256, 0, stream>>>(hin, batch, pool, pcnt);
    mlp_kernel<<<N_GRAPHS, 128, 0, stream>>>(
        pool, pcnt, gf, gfW1, gfb1, gfW2, gfb2, W1, b1, W2, b2, W3, b3, out);
}